// Round 1
// baseline (546.281 us; speedup 1.0000x reference)
//
#include <hip/hip_runtime.h>
#include <math.h>

#define EPSF 1e-8f
#define DDIM 32

// ---------------- Kernel A: Scott's-rule bandwidth -> inv_bw_sq ----------------
// 1 block x 1024 threads. thread = (chunk 0..31) x (dim 0..31); coalesced column sums.
__global__ __launch_bounds__(1024) void stats_kernel(const float* __restrict__ train,
                                                     int n, float* __restrict__ stats) {
    __shared__ double s1s[1024];
    __shared__ double s2s[1024];
    __shared__ float stds[DDIM];
    int tid = threadIdx.x;
    int dim = tid & (DDIM - 1);
    int chunk = tid >> 5;              // 0..31
    int rows = n >> 5;                 // rows per chunk (256 for n=8192)
    int r0 = chunk * rows;
    double s1 = 0.0, s2 = 0.0;
    for (int i = 0; i < rows; ++i) {
        float v = train[(r0 + i) * DDIM + dim];
        s1 += (double)v;
        s2 += (double)v * (double)v;
    }
    s1s[tid] = s1;
    s2s[tid] = s2;
    __syncthreads();
    if (tid < DDIM) {
        double a = 0.0, b = 0.0;
        for (int c = 0; c < 32; ++c) {
            a += s1s[c * DDIM + tid];
            b += s2s[c * DDIM + tid];
        }
        double var = (b - a * a / (double)n) / (double)(n - 1);  // ddof=1
        stds[tid] = (float)sqrt(var);
    }
    __syncthreads();
    if (tid == 0) {
        float mean_std = 0.f;
        for (int k = 0; k < DDIM; ++k) mean_std += stds[k];
        mean_std *= (1.0f / (float)DDIM);
        float bw = mean_std * powf((float)n, -1.0f / (float)(DDIM + 4));
        float c = 1.0f / (2.0f * bw * bw);
        stats[0] = c;
    }
}

// ---------------- Kernel B: per-train-row squared norms ----------------
__global__ __launch_bounds__(256) void tnorm_kernel(const float* __restrict__ train,
                                                    int n, float* __restrict__ tnorm) {
    int j = blockIdx.x * 256 + threadIdx.x;
    if (j >= n) return;
    const float4* row = (const float4*)(train + (size_t)j * DDIM);
    float s = 0.f;
#pragma unroll
    for (int k = 0; k < DDIM / 4; ++k) {
        float4 t = row[k];
        s = fmaf(t.x, t.x, s);
        s = fmaf(t.y, t.y, s);
        s = fmaf(t.z, t.z, s);
        s = fmaf(t.w, t.w, s);
    }
    tnorm[j] = s;
}

__device__ __forceinline__ float dp4(float4 a, float4 b, float acc) {
    acc = fmaf(a.x, b.x, acc);
    acc = fmaf(a.y, b.y, acc);
    acc = fmaf(a.z, b.z, acc);
    acc = fmaf(a.w, b.w, acc);
    return acc;
}

// ---------------- Kernel C: fused KDE sweep ----------------
// grid = (m/256 query blocks, nchunks train chunks). Each thread owns one query
// in VGPRs; train row index j is wave-uniform -> rows load as scalar (SGPR)
// broadcasts, inner loop is pure v_fma_f32. Partial num/den per chunk to ws.
__global__ __launch_bounds__(256) void kde_kernel(const float* __restrict__ x,
                                                  const float* __restrict__ train,
                                                  const float* __restrict__ resid,
                                                  const float* __restrict__ tnorm,
                                                  const float* __restrict__ stats,
                                                  int m, int n, int nchunks,
                                                  float* __restrict__ numP,
                                                  float* __restrict__ denP) {
    int q = blockIdx.x * 256 + threadIdx.x;
    int s = blockIdx.y;
    int chunk = n / nchunks;
    int j0 = s * chunk;
    int j1 = j0 + chunk;

    float c = stats[0];
    float negc = -c;

    const float4* xrow = (const float4*)(x + (size_t)q * DDIM);
    float4 x0 = xrow[0], x1 = xrow[1], x2 = xrow[2], x3 = xrow[3];
    float4 x4 = xrow[4], x5 = xrow[5], x6 = xrow[6], x7 = xrow[7];

    float qn = 0.f;
    qn = dp4(x0, x0, qn); qn = dp4(x1, x1, qn); qn = dp4(x2, x2, qn); qn = dp4(x3, x3, qn);
    qn = dp4(x4, x4, qn); qn = dp4(x5, x5, qn); qn = dp4(x6, x6, qn); qn = dp4(x7, x7, qn);

    float num = 0.f, den = 0.f;

#pragma unroll 2
    for (int j = j0; j < j1; ++j) {
        const float4* trow = (const float4*)(train + (size_t)j * DDIM);
        float4 t0 = trow[0], t1 = trow[1], t2 = trow[2], t3 = trow[3];
        float4 t4 = trow[4], t5 = trow[5], t6 = trow[6], t7 = trow[7];
        float tn = tnorm[j];
        float rj = resid[j];

        // 4 independent FMA chains for ILP
        float dA = 0.f, dB = 0.f, dC = 0.f, dD = 0.f;
        dA = dp4(x0, t0, dA); dB = dp4(x1, t1, dB);
        dC = dp4(x2, t2, dC); dD = dp4(x3, t3, dD);
        dA = dp4(x4, t4, dA); dB = dp4(x5, t5, dB);
        dC = dp4(x6, t6, dC); dD = dp4(x7, t7, dD);
        float dot = (dA + dB) + (dC + dD);

        float d2 = fmaf(-2.0f, dot, qn + tn);
        d2 = fmaxf(d2, 0.0f);
        float w = __expf(negc * d2);
        num = fmaf(w, rj, num);
        den += w;
    }

    numP[(size_t)s * m + q] = num;
    denP[(size_t)s * m + q] = den;
}

// ---------------- Kernel D: reduce partials, min-max normalize, combine ----------------
__global__ __launch_bounds__(1024) void finalize_kernel(const float* __restrict__ numP,
                                                        const float* __restrict__ denP,
                                                        const float* __restrict__ sigma,
                                                        float* __restrict__ rxbuf,
                                                        float* __restrict__ out,
                                                        int m, int nchunks) {
    __shared__ float red[1024];
    int tid = threadIdx.x;

    float rxmin = INFINITY, rxmax = -INFINITY;
    float smin = INFINITY, smax = -INFINITY;

    for (int q = tid; q < m; q += 1024) {
        float num = 0.f, den = 0.f;
        for (int s = 0; s < nchunks; ++s) {
            num += numP[(size_t)s * m + q];
            den += denP[(size_t)s * m + q];
        }
        float rx = num / (den + EPSF);
        rxbuf[q] = rx;
        rxmin = fminf(rxmin, rx);
        rxmax = fmaxf(rxmax, rx);
        float sg = sigma[q];
        smin = fminf(smin, sg);
        smax = fmaxf(smax, sg);
    }

    // 4 sequential LDS tree reductions
    red[tid] = rxmin; __syncthreads();
    for (int o = 512; o > 0; o >>= 1) { if (tid < o) red[tid] = fminf(red[tid], red[tid + o]); __syncthreads(); }
    rxmin = red[0]; __syncthreads();

    red[tid] = rxmax; __syncthreads();
    for (int o = 512; o > 0; o >>= 1) { if (tid < o) red[tid] = fmaxf(red[tid], red[tid + o]); __syncthreads(); }
    rxmax = red[0]; __syncthreads();

    red[tid] = smin; __syncthreads();
    for (int o = 512; o > 0; o >>= 1) { if (tid < o) red[tid] = fminf(red[tid], red[tid + o]); __syncthreads(); }
    smin = red[0]; __syncthreads();

    red[tid] = smax; __syncthreads();
    for (int o = 512; o > 0; o >>= 1) { if (tid < o) red[tid] = fmaxf(red[tid], red[tid + o]); __syncthreads(); }
    smax = red[0]; __syncthreads();

    float invr = 1.0f / (rxmax - rxmin + EPSF);
    float invs = 1.0f / (smax - smin + EPSF);

    for (int q = tid; q < m; q += 1024) {
        float t1 = 0.5f * (rxbuf[q] - rxmin) * invr;
        float t2 = 0.5f * (sigma[q] - smin) * invs;
        out[q] = t1 + t2;
    }
}

extern "C" void kernel_launch(void* const* d_in, const int* in_sizes, int n_in,
                              void* d_out, int out_size, void* d_ws, size_t ws_size,
                              hipStream_t stream) {
    const float* x      = (const float*)d_in[0];  // [nr, nb, 32]
    const float* train  = (const float*)d_in[1];  // [n, 32]
    const float* resid  = (const float*)d_in[2];  // [n]
    const float* sigma  = (const float*)d_in[3];  // [nr, nb]
    float* out = (float*)d_out;

    int n = in_sizes[2];          // 8192
    int m = in_sizes[3];          // 16384
    int nchunks = n / 1024;       // 8
    if (nchunks < 1) nchunks = 1;

    // ws layout (floats)
    float* ws    = (float*)d_ws;
    float* stats = ws;                         // [16]
    float* tnorm = ws + 16;                    // [n]
    float* numP  = tnorm + n;                  // [nchunks*m]
    float* denP  = numP + (size_t)nchunks * m; // [nchunks*m]
    float* rxbuf = denP + (size_t)nchunks * m; // [m]

    stats_kernel<<<1, 1024, 0, stream>>>(train, n, stats);
    tnorm_kernel<<<(n + 255) / 256, 256, 0, stream>>>(train, n, tnorm);

    dim3 grid_c(m / 256, nchunks);
    kde_kernel<<<grid_c, 256, 0, stream>>>(x, train, resid, tnorm, stats,
                                           m, n, nchunks, numP, denP);

    finalize_kernel<<<1, 1024, 0, stream>>>(numP, denP, sigma, rxbuf, out, m, nchunks);
}

// Round 2
// 235.612 us; speedup vs baseline: 2.3186x; 2.3186x over previous
//
#include <hip/hip_runtime.h>
#include <math.h>

#define EPSF 1e-8f
#define DDIM 32

__device__ __forceinline__ float dp4(float4 a, float4 b, float acc) {
    acc = fmaf(a.x, b.x, acc);
    acc = fmaf(a.y, b.y, acc);
    acc = fmaf(a.z, b.z, acc);
    acc = fmaf(a.w, b.w, acc);
    return acc;
}

// ---------------- Stats phase 1: per-block column sums (32 blocks) ----------------
__global__ __launch_bounds__(256) void stats_part(const float* __restrict__ train, int n,
                                                  double* __restrict__ pS1,
                                                  double* __restrict__ pS2) {
    __shared__ double s1s[256];
    __shared__ double s2s[256];
    int tid = threadIdx.x;
    int dim = tid & 31;
    int grp = tid >> 5;                 // 0..7
    int rowsPerBlock = n >> 5;          // n/32 (256 for n=8192)
    int rpt = rowsPerBlock >> 3;        // rows per thread
    int r0 = blockIdx.x * rowsPerBlock + grp * rpt;
    double s1 = 0.0, s2 = 0.0;
    for (int i = 0; i < rpt; ++i) {
        float v = train[(size_t)(r0 + i) * DDIM + dim];
        s1 += (double)v;
        s2 += (double)v * (double)v;
    }
    s1s[tid] = s1;
    s2s[tid] = s2;
    __syncthreads();
    if (tid < 32) {
        double a = 0.0, b = 0.0;
        for (int g = 0; g < 8; ++g) { a += s1s[g * 32 + tid]; b += s2s[g * 32 + tid]; }
        pS1[blockIdx.x * 32 + tid] = a;
        pS2[blockIdx.x * 32 + tid] = b;
    }
}

// ---------------- Stats phase 2: combine, Scott's rule -> inv_bw_sq ----------------
__global__ __launch_bounds__(64) void stats_fin(const double* __restrict__ pS1,
                                                const double* __restrict__ pS2,
                                                int n, float* __restrict__ stats) {
    __shared__ float stds[32];
    int tid = threadIdx.x;
    if (tid < 32) {
        double a = 0.0, b = 0.0;
        for (int k = 0; k < 32; ++k) { a += pS1[k * 32 + tid]; b += pS2[k * 32 + tid]; }
        double var = (b - a * a / (double)n) / (double)(n - 1);  // ddof=1
        stds[tid] = (float)sqrt(var);
    }
    __syncthreads();
    if (tid == 0) {
        float ms = 0.f;
        for (int k = 0; k < DDIM; ++k) ms += stds[k];
        ms *= (1.0f / (float)DDIM);
        float bw = ms * powf((float)n, -1.0f / (float)(DDIM + 4));
        stats[0] = 1.0f / (2.0f * bw * bw);
    }
}

// ---------------- Train-row squared norms ----------------
__global__ __launch_bounds__(256) void tnorm_kernel(const float* __restrict__ train,
                                                    int n, float* __restrict__ tnorm) {
    int j = blockIdx.x * 256 + threadIdx.x;
    if (j >= n) return;
    const float4* row = (const float4*)(train + (size_t)j * DDIM);
    float s = 0.f;
#pragma unroll
    for (int k = 0; k < DDIM / 4; ++k) {
        float4 t = row[k];
        s = fmaf(t.x, t.x, s); s = fmaf(t.y, t.y, s);
        s = fmaf(t.z, t.z, s); s = fmaf(t.w, t.w, s);
    }
    tnorm[j] = s;
}

// ---------------- Main KDE sweep: 2 queries/thread, train rows via SGPR ----------------
// __launch_bounds__(256,4): 4 waves/EU -> 128-VGPR budget so both query vectors
// stay register-resident (round-1's default bound forced a 64-VGPR budget,
// VGPR_Count=24 => query reloaded in-loop => latency-bound at 25% VALUBusy).
__global__ __launch_bounds__(256, 4) void kde_kernel(const float* __restrict__ x,
                                                     const float* __restrict__ train,
                                                     const float* __restrict__ resid,
                                                     const float* __restrict__ tnorm,
                                                     const float* __restrict__ stats,
                                                     int m, int n, int nchunks,
                                                     float* __restrict__ numP,
                                                     float* __restrict__ denP) {
    int t = blockIdx.x * 256 + threadIdx.x;   // 0 .. m/2-1
    int qa = t;
    int qb = t + (m >> 1);
    int s = blockIdx.y;
    int chunk = n / nchunks;
    int j0 = s * chunk, j1 = j0 + chunk;
    float negc = -stats[0];

    const float4* xa = (const float4*)(x + (size_t)qa * DDIM);
    const float4* xb = (const float4*)(x + (size_t)qb * DDIM);
    float4 a0 = xa[0], a1 = xa[1], a2 = xa[2], a3 = xa[3];
    float4 a4 = xa[4], a5 = xa[5], a6 = xa[6], a7 = xa[7];
    float4 b0 = xb[0], b1 = xb[1], b2 = xb[2], b3 = xb[3];
    float4 b4 = xb[4], b5 = xb[5], b6 = xb[6], b7 = xb[7];

    float qna = 0.f, qnb = 0.f;
    qna = dp4(a0, a0, qna); qna = dp4(a1, a1, qna); qna = dp4(a2, a2, qna); qna = dp4(a3, a3, qna);
    qna = dp4(a4, a4, qna); qna = dp4(a5, a5, qna); qna = dp4(a6, a6, qna); qna = dp4(a7, a7, qna);
    qnb = dp4(b0, b0, qnb); qnb = dp4(b1, b1, qnb); qnb = dp4(b2, b2, qnb); qnb = dp4(b3, b3, qnb);
    qnb = dp4(b4, b4, qnb); qnb = dp4(b5, b5, qnb); qnb = dp4(b6, b6, qnb); qnb = dp4(b7, b7, qnb);

    float numA = 0.f, denA = 0.f, numB = 0.f, denB = 0.f;

#pragma unroll 2
    for (int j = j0; j < j1; ++j) {
        const float4* tr = (const float4*)(train + (size_t)j * DDIM);  // wave-uniform -> s_load
        float4 t0 = tr[0], t1 = tr[1], t2 = tr[2], t3 = tr[3];
        float4 t4 = tr[4], t5 = tr[5], t6 = tr[6], t7 = tr[7];
        float tn = tnorm[j];
        float rj = resid[j];

        // 8 independent FMA chains (4 per query) for ILP
        float dA0 = 0.f, dA1 = 0.f, dA2 = 0.f, dA3 = 0.f;
        float dB0 = 0.f, dB1 = 0.f, dB2 = 0.f, dB3 = 0.f;
        dA0 = dp4(a0, t0, dA0); dB0 = dp4(b0, t0, dB0);
        dA1 = dp4(a1, t1, dA1); dB1 = dp4(b1, t1, dB1);
        dA2 = dp4(a2, t2, dA2); dB2 = dp4(b2, t2, dB2);
        dA3 = dp4(a3, t3, dA3); dB3 = dp4(b3, t3, dB3);
        dA0 = dp4(a4, t4, dA0); dB0 = dp4(b4, t4, dB0);
        dA1 = dp4(a5, t5, dA1); dB1 = dp4(b5, t5, dB1);
        dA2 = dp4(a6, t6, dA2); dB2 = dp4(b6, t6, dB2);
        dA3 = dp4(a7, t7, dA3); dB3 = dp4(b7, t7, dB3);
        float da = (dA0 + dA1) + (dA2 + dA3);
        float db = (dB0 + dB1) + (dB2 + dB3);

        float d2a = fmaxf(fmaf(-2.0f, da, qna + tn), 0.0f);
        float d2b = fmaxf(fmaf(-2.0f, db, qnb + tn), 0.0f);
        float wa = __expf(negc * d2a);
        float wb = __expf(negc * d2b);
        numA = fmaf(wa, rj, numA); denA += wa;
        numB = fmaf(wb, rj, numB); denB += wb;
    }

    numP[(size_t)s * m + qa] = numA;
    denP[(size_t)s * m + qa] = denA;
    numP[(size_t)s * m + qb] = numB;
    denP[(size_t)s * m + qb] = denB;
}

// ---------------- D1: reduce partials -> rx; per-block min/max of rx & sigma ----------------
__global__ __launch_bounds__(256) void reduce_kernel(const float* __restrict__ numP,
                                                     const float* __restrict__ denP,
                                                     const float* __restrict__ sigma,
                                                     float* __restrict__ rxbuf,
                                                     float* __restrict__ bred,
                                                     int m, int nchunks, int nb) {
    __shared__ float red[256];
    int tid = threadIdx.x;
    int q = blockIdx.x * 256 + tid;

    float num = 0.f, den = 0.f;
    for (int s = 0; s < nchunks; ++s) {
        num += numP[(size_t)s * m + q];
        den += denP[(size_t)s * m + q];
    }
    float rx = num / (den + EPSF);
    rxbuf[q] = rx;
    float sg = sigma[q];

    red[tid] = rx; __syncthreads();
    for (int o = 128; o > 0; o >>= 1) { if (tid < o) red[tid] = fminf(red[tid], red[tid + o]); __syncthreads(); }
    if (tid == 0) bred[0 * nb + blockIdx.x] = red[0];
    __syncthreads();

    red[tid] = rx; __syncthreads();
    for (int o = 128; o > 0; o >>= 1) { if (tid < o) red[tid] = fmaxf(red[tid], red[tid + o]); __syncthreads(); }
    if (tid == 0) bred[1 * nb + blockIdx.x] = red[0];
    __syncthreads();

    red[tid] = sg; __syncthreads();
    for (int o = 128; o > 0; o >>= 1) { if (tid < o) red[tid] = fminf(red[tid], red[tid + o]); __syncthreads(); }
    if (tid == 0) bred[2 * nb + blockIdx.x] = red[0];
    __syncthreads();

    red[tid] = sg; __syncthreads();
    for (int o = 128; o > 0; o >>= 1) { if (tid < o) red[tid] = fmaxf(red[tid], red[tid + o]); __syncthreads(); }
    if (tid == 0) bred[3 * nb + blockIdx.x] = red[0];
}

// ---------------- D2: global min/max -> normalization scales ----------------
__global__ __launch_bounds__(64) void scale_kernel(const float* __restrict__ bred,
                                                   int nb, float* __restrict__ scales) {
    int tid = threadIdx.x;  // one wave
    float v0 = (tid < nb) ? bred[0 * nb + tid] : INFINITY;
    float v1 = (tid < nb) ? bred[1 * nb + tid] : -INFINITY;
    float v2 = (tid < nb) ? bred[2 * nb + tid] : INFINITY;
    float v3 = (tid < nb) ? bred[3 * nb + tid] : -INFINITY;
    for (int o = 32; o > 0; o >>= 1) {
        v0 = fminf(v0, __shfl_xor(v0, o));
        v1 = fmaxf(v1, __shfl_xor(v1, o));
        v2 = fminf(v2, __shfl_xor(v2, o));
        v3 = fmaxf(v3, __shfl_xor(v3, o));
    }
    if (tid == 0) {
        scales[0] = v0;                        // rxmin
        scales[1] = 1.0f / (v1 - v0 + EPSF);   // 1/(rxmax-rxmin+eps)
        scales[2] = v2;                        // smin
        scales[3] = 1.0f / (v3 - v2 + EPSF);   // 1/(smax-smin+eps)
    }
}

// ---------------- D3: combine ----------------
__global__ __launch_bounds__(256) void combine_kernel(const float* __restrict__ rxbuf,
                                                      const float* __restrict__ sigma,
                                                      const float* __restrict__ scales,
                                                      float* __restrict__ out, int m) {
    int q = blockIdx.x * 256 + threadIdx.x;
    if (q >= m) return;
    float rxmin = scales[0], invr = scales[1], smin = scales[2], invs = scales[3];
    float t1 = 0.5f * (rxbuf[q] - rxmin) * invr;
    float t2 = 0.5f * (sigma[q] - smin) * invs;
    out[q] = t1 + t2;
}

extern "C" void kernel_launch(void* const* d_in, const int* in_sizes, int n_in,
                              void* d_out, int out_size, void* d_ws, size_t ws_size,
                              hipStream_t stream) {
    const float* x     = (const float*)d_in[0];  // [nr*nb, 32]
    const float* train = (const float*)d_in[1];  // [n, 32]
    const float* resid = (const float*)d_in[2];  // [n]
    const float* sigma = (const float*)d_in[3];  // [m]
    float* out = (float*)d_out;

    int n = in_sizes[2];   // 8192
    int m = in_sizes[3];   // 16384
    int nb = m / 256;      // 64 reduce blocks

    // ws layout: doubles first (alignment), then floats, then partials
    double* pS1   = (double*)d_ws;                 // 32*32
    double* pS2   = pS1 + 1024;                    // 32*32
    float*  stats = (float*)(pS2 + 1024);          // 16
    float*  scales = stats + 16;                   // 16
    float*  tnorm = scales + 16;                   // n
    float*  rxbuf = tnorm + n;                     // m
    float*  bred  = rxbuf + m;                     // 4*nb
    float*  numP  = bred + 4 * nb;                 // nchunks*m
    size_t baseBytes = (size_t)((char*)numP - (char*)d_ws);

    // pick largest power-of-two nchunks (<=64) whose partials fit in ws
    int nchunks = 64;
    while (nchunks > 1 &&
           baseBytes + (size_t)2 * nchunks * m * sizeof(float) > ws_size)
        nchunks >>= 1;
    float* denP = numP + (size_t)nchunks * m;

    stats_part<<<32, 256, 0, stream>>>(train, n, pS1, pS2);
    stats_fin<<<1, 64, 0, stream>>>(pS1, pS2, n, stats);
    tnorm_kernel<<<(n + 255) / 256, 256, 0, stream>>>(train, n, tnorm);

    dim3 grid_c(m / 512, nchunks);   // 2 queries per thread
    kde_kernel<<<grid_c, 256, 0, stream>>>(x, train, resid, tnorm, stats,
                                           m, n, nchunks, numP, denP);

    reduce_kernel<<<nb, 256, 0, stream>>>(numP, denP, sigma, rxbuf, bred, m, nchunks, nb);
    scale_kernel<<<1, 64, 0, stream>>>(bred, nb, scales);
    combine_kernel<<<nb, 256, 0, stream>>>(rxbuf, sigma, scales, out, m);
}

// Round 3
// 228.355 us; speedup vs baseline: 2.3922x; 1.0318x over previous
//
#include <hip/hip_runtime.h>
#include <math.h>

#define EPSF 1e-8f
#define DDIM 32

// Force a float4's components to live in VGPRs at this point; the values become
// asm-defined so the compiler cannot rematerialize the originating load inside
// a later loop. (R2 evidence: VGPR_Count=48 < 64 query floats => in-loop reloads.)
#define PIN4(v) asm volatile("" : "+v"(v.x), "+v"(v.y), "+v"(v.z), "+v"(v.w))

__device__ __forceinline__ float dp4(float4 a, float4 b, float acc) {
    acc = fmaf(a.x, b.x, acc);
    acc = fmaf(a.y, b.y, acc);
    acc = fmaf(a.z, b.z, acc);
    acc = fmaf(a.w, b.w, acc);
    return acc;
}

// ---------------- Prep: train-row norms + per-block column sums (32 blocks) ----------------
__global__ __launch_bounds__(256) void prep_kernel(const float* __restrict__ train, int n,
                                                   float* __restrict__ tnorm,
                                                   double* __restrict__ pS1,
                                                   double* __restrict__ pS2) {
    __shared__ double s1s[256];
    __shared__ double s2s[256];
    int tid = threadIdx.x;
    int rowsPerBlock = n >> 5;               // n/32 (256 for n=8192)
    int rbase = blockIdx.x * rowsPerBlock;

    // Phase A: tnorm for this block's rows (coalesced float4)
    for (int r = rbase + tid; r < rbase + rowsPerBlock; r += 256) {
        const float4* row = (const float4*)(train + (size_t)r * DDIM);
        float s = 0.f;
#pragma unroll
        for (int k = 0; k < DDIM / 4; ++k) {
            float4 t = row[k];
            s = fmaf(t.x, t.x, s); s = fmaf(t.y, t.y, s);
            s = fmaf(t.z, t.z, s); s = fmaf(t.w, t.w, s);
        }
        tnorm[r] = s;
    }

    // Phase B: column partial sums (dim = lane group), data L1/L2-hot from phase A
    int dim = tid & 31;
    int grp = tid >> 5;                      // 0..7
    int rpt = rowsPerBlock >> 3;             // rows per thread
    int r0 = rbase + grp * rpt;
    double s1 = 0.0, s2 = 0.0;
    for (int i = 0; i < rpt; ++i) {
        float v = train[(size_t)(r0 + i) * DDIM + dim];
        s1 += (double)v;
        s2 += (double)v * (double)v;
    }
    s1s[tid] = s1;
    s2s[tid] = s2;
    __syncthreads();
    if (tid < 32) {
        double a = 0.0, b = 0.0;
        for (int g = 0; g < 8; ++g) { a += s1s[g * 32 + tid]; b += s2s[g * 32 + tid]; }
        pS1[blockIdx.x * 32 + tid] = a;
        pS2[blockIdx.x * 32 + tid] = b;
    }
}

// ---------------- Stats finisher: combine, Scott's rule -> inv_bw_sq ----------------
__global__ __launch_bounds__(64) void stats_fin(const double* __restrict__ pS1,
                                                const double* __restrict__ pS2,
                                                int n, float* __restrict__ stats) {
    __shared__ float stds[32];
    int tid = threadIdx.x;
    if (tid < 32) {
        double a = 0.0, b = 0.0;
        for (int k = 0; k < 32; ++k) { a += pS1[k * 32 + tid]; b += pS2[k * 32 + tid]; }
        double var = (b - a * a / (double)n) / (double)(n - 1);  // ddof=1
        stds[tid] = (float)sqrt(var);
    }
    __syncthreads();
    if (tid == 0) {
        float ms = 0.f;
        for (int k = 0; k < DDIM; ++k) ms += stds[k];
        ms *= (1.0f / (float)DDIM);
        float bw = ms * powf((float)n, -1.0f / (float)(DDIM + 4));
        stats[0] = 1.0f / (2.0f * bw * bw);
    }
}

// ---------------- Main KDE sweep: 2 queries/thread pinned in VGPRs, train rows via SGPR ----
__global__ __launch_bounds__(256, 4) void kde_kernel(const float* __restrict__ x,
                                                     const float* __restrict__ train,
                                                     const float* __restrict__ resid,
                                                     const float* __restrict__ tnorm,
                                                     const float* __restrict__ stats,
                                                     int m, int n, int nchunks,
                                                     float* __restrict__ numP,
                                                     float* __restrict__ denP) {
    int t = blockIdx.x * 256 + threadIdx.x;   // 0 .. m/2-1
    int qa = t;
    int qb = t + (m >> 1);
    int s = blockIdx.y;
    int chunk = n / nchunks;
    int j0 = s * chunk, j1 = j0 + chunk;
    float negc = -stats[0];

    const float4* xa = (const float4*)(x + (size_t)qa * DDIM);
    const float4* xb = (const float4*)(x + (size_t)qb * DDIM);
    float4 a0 = xa[0], a1 = xa[1], a2 = xa[2], a3 = xa[3];
    float4 a4 = xa[4], a5 = xa[5], a6 = xa[6], a7 = xa[7];
    float4 b0 = xb[0], b1 = xb[1], b2 = xb[2], b3 = xb[3];
    float4 b4 = xb[4], b5 = xb[5], b6 = xb[6], b7 = xb[7];
    PIN4(a0); PIN4(a1); PIN4(a2); PIN4(a3);
    PIN4(a4); PIN4(a5); PIN4(a6); PIN4(a7);
    PIN4(b0); PIN4(b1); PIN4(b2); PIN4(b3);
    PIN4(b4); PIN4(b5); PIN4(b6); PIN4(b7);

    float qna = 0.f, qnb = 0.f;
    qna = dp4(a0, a0, qna); qna = dp4(a1, a1, qna); qna = dp4(a2, a2, qna); qna = dp4(a3, a3, qna);
    qna = dp4(a4, a4, qna); qna = dp4(a5, a5, qna); qna = dp4(a6, a6, qna); qna = dp4(a7, a7, qna);
    qnb = dp4(b0, b0, qnb); qnb = dp4(b1, b1, qnb); qnb = dp4(b2, b2, qnb); qnb = dp4(b3, b3, qnb);
    qnb = dp4(b4, b4, qnb); qnb = dp4(b5, b5, qnb); qnb = dp4(b6, b6, qnb); qnb = dp4(b7, b7, qnb);

    float numA = 0.f, denA = 0.f, numB = 0.f, denB = 0.f;

#pragma unroll 2
    for (int j = j0; j < j1; ++j) {
        const float4* tr = (const float4*)(train + (size_t)j * DDIM);  // wave-uniform -> s_load
        float4 t0 = tr[0], t1 = tr[1], t2 = tr[2], t3 = tr[3];
        float4 t4 = tr[4], t5 = tr[5], t6 = tr[6], t7 = tr[7];
        float tn = tnorm[j];
        float rj = resid[j];

        // 8 independent FMA chains (4 per query) for ILP
        float dA0 = 0.f, dA1 = 0.f, dA2 = 0.f, dA3 = 0.f;
        float dB0 = 0.f, dB1 = 0.f, dB2 = 0.f, dB3 = 0.f;
        dA0 = dp4(a0, t0, dA0); dB0 = dp4(b0, t0, dB0);
        dA1 = dp4(a1, t1, dA1); dB1 = dp4(b1, t1, dB1);
        dA2 = dp4(a2, t2, dA2); dB2 = dp4(b2, t2, dB2);
        dA3 = dp4(a3, t3, dA3); dB3 = dp4(b3, t3, dB3);
        dA0 = dp4(a4, t4, dA0); dB0 = dp4(b4, t4, dB0);
        dA1 = dp4(a5, t5, dA1); dB1 = dp4(b5, t5, dB1);
        dA2 = dp4(a6, t6, dA2); dB2 = dp4(b6, t6, dB2);
        dA3 = dp4(a7, t7, dA3); dB3 = dp4(b7, t7, dB3);
        float da = (dA0 + dA1) + (dA2 + dA3);
        float db = (dB0 + dB1) + (dB2 + dB3);

        float d2a = fmaxf(fmaf(-2.0f, da, qna + tn), 0.0f);
        float d2b = fmaxf(fmaf(-2.0f, db, qnb + tn), 0.0f);
        float wa = __expf(negc * d2a);
        float wb = __expf(negc * d2b);
        numA = fmaf(wa, rj, numA); denA += wa;
        numB = fmaf(wb, rj, numB); denB += wb;
    }

    numP[(size_t)s * m + qa] = numA;
    denP[(size_t)s * m + qa] = denA;
    numP[(size_t)s * m + qb] = numB;
    denP[(size_t)s * m + qb] = denB;
}

// ---------------- Reduce partials -> rx; per-block min/max of rx & sigma ----------------
__global__ __launch_bounds__(256) void reduce_kernel(const float* __restrict__ numP,
                                                     const float* __restrict__ denP,
                                                     const float* __restrict__ sigma,
                                                     float* __restrict__ rxbuf,
                                                     float* __restrict__ bred,
                                                     int m, int nchunks, int nb) {
    __shared__ float red[256];
    int tid = threadIdx.x;
    int q = blockIdx.x * 256 + tid;

    float num = 0.f, den = 0.f;
    for (int s = 0; s < nchunks; ++s) {
        num += numP[(size_t)s * m + q];
        den += denP[(size_t)s * m + q];
    }
    float rx = num / (den + EPSF);
    rxbuf[q] = rx;
    float sg = sigma[q];

    red[tid] = rx; __syncthreads();
    for (int o = 128; o > 0; o >>= 1) { if (tid < o) red[tid] = fminf(red[tid], red[tid + o]); __syncthreads(); }
    if (tid == 0) bred[0 * nb + blockIdx.x] = red[0];
    __syncthreads();

    red[tid] = rx; __syncthreads();
    for (int o = 128; o > 0; o >>= 1) { if (tid < o) red[tid] = fmaxf(red[tid], red[tid + o]); __syncthreads(); }
    if (tid == 0) bred[1 * nb + blockIdx.x] = red[0];
    __syncthreads();

    red[tid] = sg; __syncthreads();
    for (int o = 128; o > 0; o >>= 1) { if (tid < o) red[tid] = fminf(red[tid], red[tid + o]); __syncthreads(); }
    if (tid == 0) bred[2 * nb + blockIdx.x] = red[0];
    __syncthreads();

    red[tid] = sg; __syncthreads();
    for (int o = 128; o > 0; o >>= 1) { if (tid < o) red[tid] = fmaxf(red[tid], red[tid + o]); __syncthreads(); }
    if (tid == 0) bred[3 * nb + blockIdx.x] = red[0];
}

// ---------------- Combine (fused global min/max: each block reduces the 64 extrema) -------
__global__ __launch_bounds__(256) void combine_kernel(const float* __restrict__ rxbuf,
                                                      const float* __restrict__ sigma,
                                                      const float* __restrict__ bred,
                                                      float* __restrict__ out,
                                                      int m, int nb) {
    __shared__ float sc[4];
    int tid = threadIdx.x;
    if (tid < 64) {
        float v0 = (tid < nb) ? bred[0 * nb + tid] : INFINITY;
        float v1 = (tid < nb) ? bred[1 * nb + tid] : -INFINITY;
        float v2 = (tid < nb) ? bred[2 * nb + tid] : INFINITY;
        float v3 = (tid < nb) ? bred[3 * nb + tid] : -INFINITY;
        for (int o = 32; o > 0; o >>= 1) {
            v0 = fminf(v0, __shfl_xor(v0, o));
            v1 = fmaxf(v1, __shfl_xor(v1, o));
            v2 = fminf(v2, __shfl_xor(v2, o));
            v3 = fmaxf(v3, __shfl_xor(v3, o));
        }
        if (tid == 0) {
            sc[0] = v0;
            sc[1] = 1.0f / (v1 - v0 + EPSF);
            sc[2] = v2;
            sc[3] = 1.0f / (v3 - v2 + EPSF);
        }
    }
    __syncthreads();
    int q = blockIdx.x * 256 + tid;
    if (q >= m) return;
    float t1 = 0.5f * (rxbuf[q] - sc[0]) * sc[1];
    float t2 = 0.5f * (sigma[q] - sc[2]) * sc[3];
    out[q] = t1 + t2;
}

extern "C" void kernel_launch(void* const* d_in, const int* in_sizes, int n_in,
                              void* d_out, int out_size, void* d_ws, size_t ws_size,
                              hipStream_t stream) {
    const float* x     = (const float*)d_in[0];  // [nr*nb, 32]
    const float* train = (const float*)d_in[1];  // [n, 32]
    const float* resid = (const float*)d_in[2];  // [n]
    const float* sigma = (const float*)d_in[3];  // [m]
    float* out = (float*)d_out;

    int n = in_sizes[2];   // 8192
    int m = in_sizes[3];   // 16384
    int nb = m / 256;      // 64 reduce blocks

    // ws layout: doubles first (alignment), then floats, then partials
    double* pS1    = (double*)d_ws;                // 32*32
    double* pS2    = pS1 + 1024;                   // 32*32
    float*  stats  = (float*)(pS2 + 1024);         // 16
    float*  tnorm  = stats + 16;                   // n
    float*  rxbuf  = tnorm + n;                    // m
    float*  bred   = rxbuf + m;                    // 4*nb
    float*  numP   = bred + 4 * nb;                // nchunks*m
    size_t baseBytes = (size_t)((char*)numP - (char*)d_ws);

    // nchunks=32 -> grid 1024 blocks = exactly 4 blocks/CU (one residency pass
    // at the __launch_bounds__(256,4) cap). Shrink if ws is too small.
    int nchunks = 32;
    while (nchunks > 1 &&
           baseBytes + (size_t)2 * nchunks * m * sizeof(float) > ws_size)
        nchunks >>= 1;
    float* denP = numP + (size_t)nchunks * m;

    prep_kernel<<<32, 256, 0, stream>>>(train, n, tnorm, pS1, pS2);
    stats_fin<<<1, 64, 0, stream>>>(pS1, pS2, n, stats);

    dim3 grid_c(m / 512, nchunks);   // 2 queries per thread
    kde_kernel<<<grid_c, 256, 0, stream>>>(x, train, resid, tnorm, stats,
                                           m, n, nchunks, numP, denP);

    reduce_kernel<<<nb, 256, 0, stream>>>(numP, denP, sigma, rxbuf, bred, m, nchunks, nb);
    combine_kernel<<<nb, 256, 0, stream>>>(rxbuf, sigma, bred, out, m, nb);
}

// Round 4
// 137.290 us; speedup vs baseline: 3.9790x; 1.6633x over previous
//
#include <hip/hip_runtime.h>
#include <math.h>

#define EPSF 1e-8f
#define LOG2E 1.44269504f

typedef short short8 __attribute__((ext_vector_type(8)));
typedef float floatx4 __attribute__((ext_vector_type(4)));

__device__ __forceinline__ unsigned short f2bf(float f) {
    unsigned u = __builtin_bit_cast(unsigned, f);
    unsigned r = (u + 0x7FFFu + ((u >> 16) & 1u)) >> 16;   // RNE
    return (unsigned short)r;
}
__device__ __forceinline__ float bf2f(unsigned short h) {
    return __builtin_bit_cast(float, ((unsigned)h) << 16);
}

// ---- Prep: blocks 0..31: train bf16 hi/lo + tnorm + stats partials; blocks 32..: qn ----
__global__ __launch_bounds__(256) void prep_kernel(const float* __restrict__ x,
                                                   const float* __restrict__ train,
                                                   int n, int m,
                                                   float* __restrict__ tnorm,
                                                   float* __restrict__ qn,
                                                   unsigned short* __restrict__ thi,
                                                   unsigned short* __restrict__ tlo,
                                                   double* __restrict__ pS1,
                                                   double* __restrict__ pS2) {
    int tid = threadIdx.x;
    int b = blockIdx.x;
    if (b < 32) {
        __shared__ double s1s[256];
        __shared__ double s2s[256];
        int rowsPerBlock = n >> 5;          // 256
        int rbase = b * rowsPerBlock;
        for (int r = rbase + tid; r < rbase + rowsPerBlock; r += 256) {
            const float4* row = (const float4*)(train + (size_t)r * 32);
            float s = 0.f;
#pragma unroll
            for (int kb = 0; kb < 4; ++kb) {
                float4 f0 = row[kb * 2], f1 = row[kb * 2 + 1];
                float fv[8] = {f0.x, f0.y, f0.z, f0.w, f1.x, f1.y, f1.z, f1.w};
                short8 h, l;
#pragma unroll
                for (int j = 0; j < 8; ++j) {
                    unsigned short hb = f2bf(fv[j]);
                    h[j] = (short)hb;
                    l[j] = (short)f2bf(fv[j] - bf2f(hb));
                    s = fmaf(fv[j], fv[j], s);
                }
                *(short8*)(thi + (size_t)r * 32 + kb * 8) = h;
                *(short8*)(tlo + (size_t)r * 32 + kb * 8) = l;
            }
            tnorm[r] = s;
        }
        // stats partials (column sums, fp64)
        int dim = tid & 31;
        int grp = tid >> 5;
        int rpt = rowsPerBlock >> 3;
        int r0 = rbase + grp * rpt;
        double s1 = 0.0, s2 = 0.0;
        for (int i = 0; i < rpt; ++i) {
            float v = train[(size_t)(r0 + i) * 32 + dim];
            s1 += (double)v;
            s2 += (double)v * (double)v;
        }
        s1s[tid] = s1;
        s2s[tid] = s2;
        __syncthreads();
        if (tid < 32) {
            double a = 0.0, c2 = 0.0;
            for (int g = 0; g < 8; ++g) { a += s1s[g * 32 + tid]; c2 += s2s[g * 32 + tid]; }
            pS1[b * 32 + tid] = a;
            pS2[b * 32 + tid] = c2;
        }
    } else {
        int r = (b - 32) * 256 + tid;
        if (r < m) {
            const float4* row = (const float4*)(x + (size_t)r * 32);
            float s = 0.f;
#pragma unroll
            for (int k = 0; k < 8; ++k) {
                float4 t = row[k];
                s = fmaf(t.x, t.x, s); s = fmaf(t.y, t.y, s);
                s = fmaf(t.z, t.z, s); s = fmaf(t.w, t.w, s);
            }
            qn[r] = s;
        }
    }
}

// ---- KDE via MFMA: 2-term bf16 split, M=32/wave, N-tiles of 16, K=32 in one MFMA ----
// wave-local: A-frags (hi/lo) for 2 M-subtiles; per N-tile: 2 B-frag loads + 6 MFMA +
// 8-value exp epilogue per lane. Scott's c computed in block prologue from pS1/pS2.
__global__ __launch_bounds__(256, 4) void kde_kernel(const float* __restrict__ x,
                                                     const unsigned short* __restrict__ thi,
                                                     const unsigned short* __restrict__ tlo,
                                                     const float* __restrict__ resid,
                                                     const float* __restrict__ tnorm,
                                                     const float* __restrict__ qn,
                                                     const double* __restrict__ pS1,
                                                     const double* __restrict__ pS2,
                                                     int m, int n, int nchunks,
                                                     float* __restrict__ numP,
                                                     float* __restrict__ denP) {
    __shared__ double sred[32];
    __shared__ float sC[2];   // negcl, C2
    int tid = threadIdx.x;

    // --- Scott's rule prologue (per block; pS1/pS2 are tiny and L2-hot) ---
    if (tid < 32) {
        double a = 0.0, b2 = 0.0;
        for (int k = 0; k < 32; ++k) { a += pS1[k * 32 + tid]; b2 += pS2[k * 32 + tid]; }
        double var = (b2 - a * a / (double)n) / (double)(n - 1);  // ddof=1
        sred[tid] = sqrt(var);
    }
    __syncthreads();
    if (tid == 0) {
        float ms = 0.f;
        for (int k = 0; k < 32; ++k) ms += (float)sred[k];
        ms *= (1.0f / 32.0f);
        float bw = ms * powf((float)n, -1.0f / 36.0f);
        float c = 1.0f / (2.0f * bw * bw);
        sC[0] = -c * LOG2E;        // negcl
        sC[1] = 2.0f * c * LOG2E;  // C2
    }
    __syncthreads();
    float negcl = sC[0], C2 = sC[1];

    int lane = tid & 63;
    int wave = tid >> 6;
    int col = lane & 15;      // A m-index / B n-index / D col
    int quad = lane >> 4;     // D rows = quad*4 + r
    int Mbase = blockIdx.x * 128 + wave * 32;
    int chunk = n / nchunks;
    int Nstart = blockIdx.y * chunk;

    // --- A fragments: queries -> bf16 hi/lo, kept in VGPRs ---
    short8 ah[2], al[2];
#pragma unroll
    for (int s = 0; s < 2; ++s) {
        const float* xp = x + (size_t)(Mbase + s * 16 + col) * 32 + quad * 8;
        float4 f0 = *(const float4*)xp;
        float4 f1 = *(const float4*)(xp + 4);
        float fv[8] = {f0.x, f0.y, f0.z, f0.w, f1.x, f1.y, f1.z, f1.w};
#pragma unroll
        for (int j = 0; j < 8; ++j) {
            unsigned short hb = f2bf(fv[j]);
            ah[s][j] = (short)hb;
            al[s][j] = (short)f2bf(fv[j] - bf2f(hb));
        }
    }

    // --- per-row log2-domain query-norm term ---
    float alpha[2][4];
#pragma unroll
    for (int s = 0; s < 2; ++s)
#pragma unroll
        for (int r = 0; r < 4; ++r)
            alpha[s][r] = negcl * qn[Mbase + s * 16 + quad * 4 + r];

    float num[2][4] = {{0.f, 0.f, 0.f, 0.f}, {0.f, 0.f, 0.f, 0.f}};
    float den[2][4] = {{0.f, 0.f, 0.f, 0.f}, {0.f, 0.f, 0.f, 0.f}};

#pragma unroll 2
    for (int t = 0; t < chunk; t += 16) {
        int row = Nstart + t + col;
        const short8 bh = *(const short8*)(thi + (size_t)row * 32 + quad * 8);
        const short8 bl = *(const short8*)(tlo + (size_t)row * 32 + quad * 8);
        float beta = negcl * tnorm[row];   // per-col (lane) train-norm term
        float rv = resid[row];

#pragma unroll
        for (int s = 0; s < 2; ++s) {
            floatx4 acc = {0.f, 0.f, 0.f, 0.f};
            acc = __builtin_amdgcn_mfma_f32_16x16x32_bf16(ah[s], bh, acc, 0, 0, 0);
            acc = __builtin_amdgcn_mfma_f32_16x16x32_bf16(ah[s], bl, acc, 0, 0, 0);
            acc = __builtin_amdgcn_mfma_f32_16x16x32_bf16(al[s], bh, acc, 0, 0, 0);
#pragma unroll
            for (int r = 0; r < 4; ++r) {
                float arg = fminf(fmaf(C2, acc[r], alpha[s][r] + beta), 0.0f);
                float w = exp2f(arg);      // single v_exp_f32
                num[s][r] = fmaf(w, rv, num[s][r]);
                den[s][r] += w;
            }
        }
    }

    // --- reduce across the 16 lanes sharing each row set (xor 1,2,4,8) ---
#pragma unroll
    for (int s = 0; s < 2; ++s)
#pragma unroll
        for (int r = 0; r < 4; ++r) {
#pragma unroll
            for (int msk = 1; msk < 16; msk <<= 1) {
                num[s][r] += __shfl_xor(num[s][r], msk);
                den[s][r] += __shfl_xor(den[s][r], msk);
            }
        }
    if (col == 0) {
#pragma unroll
        for (int s = 0; s < 2; ++s)
#pragma unroll
            for (int r = 0; r < 4; ++r) {
                int q = Mbase + s * 16 + quad * 4 + r;
                numP[(size_t)blockIdx.y * m + q] = num[s][r];
                denP[(size_t)blockIdx.y * m + q] = den[s][r];
            }
    }
}

// ---- Reduce partials -> rx; per-block min/max of rx & sigma ----
__global__ __launch_bounds__(256) void reduce_kernel(const float* __restrict__ numP,
                                                     const float* __restrict__ denP,
                                                     const float* __restrict__ sigma,
                                                     float* __restrict__ rxbuf,
                                                     float* __restrict__ bred,
                                                     int m, int nchunks, int nb) {
    __shared__ float red[256];
    int tid = threadIdx.x;
    int q = blockIdx.x * 256 + tid;

    float num = 0.f, den = 0.f;
    for (int s = 0; s < nchunks; ++s) {
        num += numP[(size_t)s * m + q];
        den += denP[(size_t)s * m + q];
    }
    float rx = num / (den + EPSF);
    rxbuf[q] = rx;
    float sg = sigma[q];

    red[tid] = rx; __syncthreads();
    for (int o = 128; o > 0; o >>= 1) { if (tid < o) red[tid] = fminf(red[tid], red[tid + o]); __syncthreads(); }
    if (tid == 0) bred[0 * nb + blockIdx.x] = red[0];
    __syncthreads();
    red[tid] = rx; __syncthreads();
    for (int o = 128; o > 0; o >>= 1) { if (tid < o) red[tid] = fmaxf(red[tid], red[tid + o]); __syncthreads(); }
    if (tid == 0) bred[1 * nb + blockIdx.x] = red[0];
    __syncthreads();
    red[tid] = sg; __syncthreads();
    for (int o = 128; o > 0; o >>= 1) { if (tid < o) red[tid] = fminf(red[tid], red[tid + o]); __syncthreads(); }
    if (tid == 0) bred[2 * nb + blockIdx.x] = red[0];
    __syncthreads();
    red[tid] = sg; __syncthreads();
    for (int o = 128; o > 0; o >>= 1) { if (tid < o) red[tid] = fmaxf(red[tid], red[tid + o]); __syncthreads(); }
    if (tid == 0) bred[3 * nb + blockIdx.x] = red[0];
}

// ---- Combine: each block redundantly reduces the 64 block-extrema, then writes slice ----
__global__ __launch_bounds__(256) void combine_kernel(const float* __restrict__ rxbuf,
                                                      const float* __restrict__ sigma,
                                                      const float* __restrict__ bred,
                                                      float* __restrict__ out,
                                                      int m, int nb) {
    __shared__ float sc[4];
    int tid = threadIdx.x;
    if (tid < 64) {
        float v0 = (tid < nb) ? bred[0 * nb + tid] : INFINITY;
        float v1 = (tid < nb) ? bred[1 * nb + tid] : -INFINITY;
        float v2 = (tid < nb) ? bred[2 * nb + tid] : INFINITY;
        float v3 = (tid < nb) ? bred[3 * nb + tid] : -INFINITY;
        for (int o = 32; o > 0; o >>= 1) {
            v0 = fminf(v0, __shfl_xor(v0, o));
            v1 = fmaxf(v1, __shfl_xor(v1, o));
            v2 = fminf(v2, __shfl_xor(v2, o));
            v3 = fmaxf(v3, __shfl_xor(v3, o));
        }
        if (tid == 0) {
            sc[0] = v0;
            sc[1] = 1.0f / (v1 - v0 + EPSF);
            sc[2] = v2;
            sc[3] = 1.0f / (v3 - v2 + EPSF);
        }
    }
    __syncthreads();
    int q = blockIdx.x * 256 + tid;
    if (q >= m) return;
    float t1 = 0.5f * (rxbuf[q] - sc[0]) * sc[1];
    float t2 = 0.5f * (sigma[q] - sc[2]) * sc[3];
    out[q] = t1 + t2;
}

extern "C" void kernel_launch(void* const* d_in, const int* in_sizes, int n_in,
                              void* d_out, int out_size, void* d_ws, size_t ws_size,
                              hipStream_t stream) {
    const float* x     = (const float*)d_in[0];  // [m, 32]
    const float* train = (const float*)d_in[1];  // [n, 32]
    const float* resid = (const float*)d_in[2];  // [n]
    const float* sigma = (const float*)d_in[3];  // [m]
    float* out = (float*)d_out;

    int n = in_sizes[2];   // 8192
    int m = in_sizes[3];   // 16384
    int nb = m / 256;      // 64

    // ws layout: fp64 first, then fp32, then bf16 arrays, then partials
    double* pS1   = (double*)d_ws;                  // 32*32
    double* pS2   = pS1 + 1024;                     // 32*32
    float*  tnorm = (float*)(pS2 + 1024);           // n
    float*  qn    = tnorm + n;                      // m
    float*  rxbuf = qn + m;                         // m
    float*  bred  = rxbuf + m;                      // 4*nb
    unsigned short* thi = (unsigned short*)(bred + 4 * nb);  // n*32
    unsigned short* tlo = thi + (size_t)n * 32;              // n*32
    float* numP = (float*)(tlo + (size_t)n * 32);
    size_t baseBytes = (size_t)((char*)numP - (char*)d_ws);

    // nchunks=16 -> grid (m/128, 16) = 2048 blocks = 2 residency passes at
    // 4 blocks/CU (R3 lesson: single-pass grids expose ramp/tail).
    int nchunks = 16;
    while (nchunks > 1 &&
           baseBytes + (size_t)2 * nchunks * m * sizeof(float) > ws_size)
        nchunks >>= 1;
    float* denP = numP + (size_t)nchunks * m;

    prep_kernel<<<32 + (m + 255) / 256, 256, 0, stream>>>(x, train, n, m, tnorm, qn,
                                                          thi, tlo, pS1, pS2);

    dim3 grid_c(m / 128, nchunks);   // 4 waves/block, M=32 per wave
    kde_kernel<<<grid_c, 256, 0, stream>>>(x, thi, tlo, resid, tnorm, qn,
                                           pS1, pS2, m, n, nchunks, numP, denP);

    reduce_kernel<<<nb, 256, 0, stream>>>(numP, denP, sigma, rxbuf, bred, m, nchunks, nb);
    combine_kernel<<<nb, 256, 0, stream>>>(rxbuf, sigma, bred, out, m, nb);
}